// Round 7
// baseline (217.236 us; speedup 1.0000x reference)
//
#include <hip/hip_runtime.h>
#include <cstdio>
#include <cstdint>

// ---------------------------------------------------------------------------
// Transformer-XL relative MHA, MI355X/gfx950.  B=16 T=512 D=512 H=8 hd=64.
// Round 18: R17 profile showed (a) flash restage worked (dropped below proj),
// (b) ~84us/iter is harness ws re-poison (fillBufferAligned, 268MB @ 80%
// peak) -> controllable kernel budget ~125us. proj_all still top (41.7us,
// occupancy 14.7%: 64KB LDS caps 2 blocks/CU -> no cross-block overlap to
// hide staging). Fix: BK 64->32, LDS 32KB -> 4-5 blocks/CU, doubled TLP.
// Per step: 4 gload_lds16/wave + 8 ds_read_b128 + 16 MFMA, 16 steps,
// stage-ahead before compute, 1 barrier/step. K accumulation order unchanged
// -> bit-identical. Same for out_gemm. flash_attn/megaprep = R17.
// pack(r,k) = (r>>4)*8192 + (k>>5)*512 + ((k>>3)&3)*128 + (r&15)*8 + (k&7)
// ---------------------------------------------------------------------------

typedef short s16x8 __attribute__((ext_vector_type(8)));
typedef float f32x4 __attribute__((ext_vector_type(4)));
typedef unsigned short u16x4 __attribute__((ext_vector_type(4)));
typedef unsigned short u16x8 __attribute__((ext_vector_type(8)));

#define CSCALE 0.1803368801111204f  // log2(e)/8

#if __has_builtin(__builtin_amdgcn_exp2f)
#define EXP2(x) __builtin_amdgcn_exp2f(x)
#else
#define EXP2(x) exp2f(x)
#endif

__device__ __forceinline__ unsigned short f2bf(float f) {  // RNE
  unsigned int u = __builtin_bit_cast(unsigned int, f);
  unsigned int r = (u + 0x7FFFu + ((u >> 16) & 1u)) >> 16;
  return (unsigned short)r;
}
__device__ __forceinline__ float bf2f(unsigned short h) {
  unsigned int u = ((unsigned int)h) << 16;
  return __builtin_bit_cast(float, u);
}
// fragment-strip packing: strips of 16 rows x 512 k (8192 shorts)
__device__ __forceinline__ size_t pk(int row, int col) {
  return (size_t)(row >> 4) * 8192 + (col >> 5) * 512 + ((col >> 3) & 3) * 128 +
         (row & 15) * 8 + (col & 7);
}

// async global->LDS, 16B per lane. Global src is PER-LANE; LDS dst is the
// wave-uniform base (HW adds lane*16).
__device__ __forceinline__ void gload_lds16(const unsigned short* g,
                                            unsigned short* l) {
  __builtin_amdgcn_global_load_lds(
      (const __attribute__((address_space(1))) unsigned int*)g,
      (__attribute__((address_space(3))) unsigned int*)l, 16, 0, 0);
}

// ---------------- fused prep (vectorized stores) ---------------------------
__global__ __launch_bounds__(256) void megaprep(
    const float* __restrict__ x, const float* __restrict__ g,
    const float* __restrict__ bb, unsigned short* __restrict__ xpk,
    const float* __restrict__ pe, unsigned short* __restrict__ pepk,
    const float* __restrict__ Wq, const float* __restrict__ Wk,
    const float* __restrict__ Wp, const float* __restrict__ Wv,
    const float* __restrict__ Wo, const float* __restrict__ bq,
    const float* __restrict__ bk, unsigned short* __restrict__ wqk,
    unsigned short* __restrict__ wpm, unsigned short* __restrict__ wvm,
    unsigned short* __restrict__ wom, float* __restrict__ bqk) {
  const int bid = blockIdx.x, tid = threadIdx.x;
  if (bid < 2048) {  // LN: row = bid*4 + wave
    const int wave = tid >> 6, lane = tid & 63;
    const int row = bid * 4 + wave;
    const int c0 = lane * 8;
    const float* xr = x + (size_t)row * 512 + c0;
    float4 v0 = *(const float4*)xr;
    float4 v1 = *(const float4*)(xr + 4);
    float vv[8] = {v0.x, v0.y, v0.z, v0.w, v1.x, v1.y, v1.z, v1.w};
    float s = 0.f, ss = 0.f;
#pragma unroll
    for (int j = 0; j < 8; ++j) { s += vv[j]; ss += vv[j] * vv[j]; }
#pragma unroll
    for (int d = 1; d < 64; d <<= 1) {
      s += __shfl_xor(s, d, 64);
      ss += __shfl_xor(ss, d, 64);
    }
    const float mu = s * (1.0f / 512.0f);
    const float var = ss * (1.0f / 512.0f) - mu * mu;
    const float rstd = rsqrtf(var + 1e-5f);
    u16x8 o;
#pragma unroll
    for (int j = 0; j < 8; ++j)
      o[j] = f2bf((vv[j] - mu) * rstd * g[c0 + j] + bb[c0 + j]);
    *(u16x8*)(xpk + pk(row, c0)) = o;
  } else if (bid < 6144) {  // pe: 8 elems/thread
    int gid = (bid - 2048) * 256 + tid;
    int e = gid * 8;  // over 16384*512
    int r = e >> 9, c = e & 511;
    int b = r >> 10, u = r & 1023;
    u16x8 o = {0, 0, 0, 0, 0, 0, 0, 0};
    if (u < 1023) {
      const float* src = pe + (size_t)(b * 1023 + u) * 512 + c;
      float4 v0 = *(const float4*)src;
      float4 v1 = *(const float4*)(src + 4);
      o[0] = f2bf(v0.x); o[1] = f2bf(v0.y); o[2] = f2bf(v0.z); o[3] = f2bf(v0.w);
      o[4] = f2bf(v1.x); o[5] = f2bf(v1.y); o[6] = f2bf(v1.z); o[7] = f2bf(v1.w);
    }
    *(u16x8*)(pepk + (size_t)b * 524288 + pk(u, c)) = o;
  } else {  // weights: 8 elems/thread
    int gid = (bid - 6144) * 256 + tid;
    int idx = gid * 8;  // over 5*262144
    int region = idx >> 18, off = idx & 262143;
    const float* src = (region == 0)   ? Wq
                       : (region == 1) ? Wk
                       : (region == 2) ? Wp
                       : (region == 3) ? Wv
                                       : Wo;
    float4 v0 = *(const float4*)(src + off);
    float4 v1 = *(const float4*)(src + off + 4);
    u16x8 o;
    o[0] = f2bf(v0.x); o[1] = f2bf(v0.y); o[2] = f2bf(v0.z); o[3] = f2bf(v0.w);
    o[4] = f2bf(v1.x); o[5] = f2bf(v1.y); o[6] = f2bf(v1.z); o[7] = f2bf(v1.w);
    int n = off >> 9, k = off & 511;
    unsigned short* dst;
    int nrow = n;
    if (region == 0) { dst = wqk; }
    else if (region == 1) { dst = wqk; nrow = n + 512; }
    else if (region == 2) { dst = wpm; }
    else if (region == 3) { dst = wvm; }
    else { dst = wom; }
    *(u16x8*)(dst + pk(nrow, k)) = o;
    if (idx < 1024) {
#pragma unroll
      for (int j = 0; j < 8; j++) {
        int ii = idx + j;
        bqk[ii] = (ii < 512) ? bq[ii] : bk[ii - 512];
      }
    }
  }
}

// ---------------- 128x128 double-buffered GEMM core, BK=32 -----------------
// 4 waves, each a 64x64 quadrant. K=512 in 16 steps of BK=32. LDS:
// 2 x (8KB A + 8KB B) = 32KB -> 4-5 blocks/CU (cross-block TLP hides the
// staging latency the per-step barrier exposes). Per step: issue STAGE(t+1)
// FIRST (4 gload_lds16/wave), then 8 ds_read_b128 + 16 MFMA on buf[t], then
// ONE barrier. SWAP=true -> mfma(B,A): lane owns one output row + 4
// consecutive cols (vector epilogue).
template <bool SWAP>
__device__ __forceinline__ void gemm128_db(
    const unsigned short* __restrict__ Apk, int astrip8,
    const unsigned short* __restrict__ Bpk, int bstrip8,
    unsigned short* __restrict__ lA, unsigned short* __restrict__ lB,
    int wave, int lane, f32x4 acc[4][4]) {
  const int wr = wave >> 1, wc = wave & 1;
  const unsigned short* ga =
      Apk + (size_t)(astrip8 + 2 * wave) * 8192 + lane * 8;
  const unsigned short* gb =
      Bpk + (size_t)(bstrip8 + 2 * wave) * 8192 + lane * 8;
  // stage chunk kc (512 shorts per strip) of strips {2w,2w+1} into buf
#define STG(kc, buf)                                                         \
  _Pragma("unroll") for (int s = 0; s < 2; ++s) {                            \
    gload_lds16(ga + (size_t)s * 8192 + (kc) * 512,                          \
                lA + (buf) * 4096 + (2 * wave + s) * 512);                   \
    gload_lds16(gb + (size_t)s * 8192 + (kc) * 512,                          \
                lB + (buf) * 4096 + (2 * wave + s) * 512);                   \
  }
  STG(0, 0);
  __syncthreads();  // buf0 ready
  const unsigned short* lar = lA + (wr * 4) * 512 + lane * 8;
  const unsigned short* lbr = lB + (wc * 4) * 512 + lane * 8;
#pragma unroll
  for (int kc = 0; kc < 16; ++kc) {
    const int cur = kc & 1;
    if (kc < 15) { STG(kc + 1, cur ^ 1); }  // stage-ahead BEFORE compute
    s16x8 af[4], bf[4];
#pragma unroll
    for (int mt = 0; mt < 4; ++mt)
      af[mt] = *(const s16x8*)(lar + cur * 4096 + mt * 512);
#pragma unroll
    for (int nt = 0; nt < 4; ++nt)
      bf[nt] = *(const s16x8*)(lbr + cur * 4096 + nt * 512);
#pragma unroll
    for (int mt = 0; mt < 4; ++mt)
#pragma unroll
      for (int nt = 0; nt < 4; ++nt)
        acc[mt][nt] =
            SWAP ? __builtin_amdgcn_mfma_f32_16x16x32_bf16(
                       bf[nt], af[mt], acc[mt][nt], 0, 0, 0)
                 : __builtin_amdgcn_mfma_f32_16x16x32_bf16(
                       af[mt], bf[nt], acc[mt][nt], 0, 0, 0);
    __syncthreads();  // drains stage(t+1) vmcnt + compute(t) lgkm
  }
#undef STG
}

// merged projections: 128x128 block tiles.
__global__ __launch_bounds__(256) void proj_all(
    const unsigned short* __restrict__ xpk, const unsigned short* __restrict__ pepk,
    const unsigned short* __restrict__ wqk, const unsigned short* __restrict__ wpm,
    const unsigned short* __restrict__ wvm, const float* __restrict__ bqk,
    const float* __restrict__ bp, const float* __restrict__ bv,
    const float* __restrict__ cbv, const float* __restrict__ pbv,
    unsigned short* __restrict__ qc, unsigned short* __restrict__ qp,
    unsigned short* __restrict__ kb, unsigned short* __restrict__ pbuf,
    unsigned short* __restrict__ vth) {
  __shared__ __align__(16) unsigned short lA[8192];  // 2 x 8KB
  __shared__ __align__(16) unsigned short lB[8192];
  const int tid = threadIdx.x, lane = tid & 63, wave = tid >> 6;
  int bid = blockIdx.x;
  bid = (bid & 7) * 160 + (bid >> 3);  // XCD swizzle (1280 % 8 == 0)
  const int wr = wave >> 1, wc = wave & 1;
  const int fr = lane & 15, hi2 = lane >> 4;
  f32x4 fz = {0.f, 0.f, 0.f, 0.f};
  f32x4 acc[4][4];
#pragma unroll
  for (int i = 0; i < 4; i++)
#pragma unroll
    for (int j = 0; j < 4; j++) acc[i][j] = fz;

  if (bid < 512) {  // qk (swapped)
    int m_t = bid >> 3, n_t = bid & 7;
    gemm128_db<true>(xpk, m_t * 8, wqk, n_t * 8, lA, lB, wave, lane, acc);
    int m0 = m_t * 128 + wr * 64, n0 = n_t * 128 + wc * 64;
#pragma unroll
    for (int nt = 0; nt < 4; ++nt) {
      int colb = n0 + nt * 16 + hi2 * 4;
      float4 b4 = *(const float4*)(bqk + colb);
      float bvv[4] = {b4.x, b4.y, b4.z, b4.w};
      if (colb < 512) {  // -> qc/qp
        int h = colb >> 6, cc = colb & 63;
        float4 c4 = *(const float4*)(cbv + colb);
        float4 p4 = *(const float4*)(pbv + colb);
        float cvv[4] = {c4.x, c4.y, c4.z, c4.w};
        float pvv[4] = {p4.x, p4.y, p4.z, p4.w};
        size_t cpart = (size_t)(cc >> 5) * 512 + ((cc & 31) >> 3) * 128 +
                       (cc & 7) + (size_t)h * 32768;
#pragma unroll
        for (int mt = 0; mt < 4; ++mt) {
          int row = m0 + mt * 16 + fr;
          int b = row >> 9, s16i = (row & 511) >> 4;
          size_t idx = ((size_t)b * 8 * 32 + s16i) * 1024 + cpart + fr * 8;
          u16x4 oc, op;
#pragma unroll
          for (int r = 0; r < 4; ++r) {
            float val = acc[mt][nt][r] + bvv[r];
            oc[r] = f2bf((val + cvv[r]) * CSCALE);
            op[r] = f2bf((val + pvv[r]) * CSCALE);
          }
          *(u16x4*)(qc + idx) = oc;
          *(u16x4*)(qp + idx) = op;
        }
      } else {  // -> kb
        int c2 = colb - 512, h = c2 >> 6, cc = c2 & 63;
        size_t cpart = (size_t)(cc >> 5) * 512 + ((cc & 31) >> 3) * 128 +
                       (cc & 7) + (size_t)h * 32768;
#pragma unroll
        for (int mt = 0; mt < 4; ++mt) {
          int row = m0 + mt * 16 + fr;
          int b = row >> 9, s16i = (row & 511) >> 4;
          size_t idx = ((size_t)b * 8 * 32 + s16i) * 1024 + cpart + fr * 8;
          u16x4 ok;
#pragma unroll
          for (int r = 0; r < 4; ++r) ok[r] = f2bf(acc[mt][nt][r] + bvv[r]);
          *(u16x4*)(kb + idx) = ok;
        }
      }
    }
  } else if (bid < 1024) {  // p (per-b packed A, swapped)
    int pid = bid - 512;
    int b = pid >> 5, rem = pid & 31;
    int m_tb = rem >> 2, n_t = rem & 3;
    gemm128_db<true>(pepk + (size_t)b * 524288, m_tb * 8, wpm, n_t * 8, lA,
                     lB, wave, lane, acc);
    int u0 = m_tb * 128 + wr * 64, n0 = n_t * 128 + wc * 64;
#pragma unroll
    for (int nt = 0; nt < 4; ++nt) {
      int colb = n0 + nt * 16 + hi2 * 4;
      float4 b4 = *(const float4*)(bp + colb);
      float bvv[4] = {b4.x, b4.y, b4.z, b4.w};
      int h = colb >> 6, cc = colb & 63;
      size_t cbase = (size_t)(b * 8 + h) * 65536 + (cc >> 5) * 512 +
                     ((cc & 31) >> 3) * 128 + (cc & 7);
#pragma unroll
      for (int mt = 0; mt < 4; ++mt) {
        int u = u0 + mt * 16 + fr;
        size_t idx = cbase + (size_t)(u >> 4) * 1024 + (u & 15) * 8;
        u16x4 o;
        if (u >= 1023) {
          o[0] = 0; o[1] = 0; o[2] = 0; o[3] = 0;
        } else {
#pragma unroll
          for (int r = 0; r < 4; ++r) o[r] = f2bf(acc[mt][nt][r] + bvv[r]);
        }
        *(u16x4*)(pbuf + idx) = o;
      }
    }
  } else {  // v -> vT packed (NOT swapped)
    int vid = bid - 1024;
    int m_t = vid >> 2, n_t = vid & 3;
    gemm128_db<false>(xpk, m_t * 8, wvm, n_t * 8, lA, lB, wave, lane, acc);
    int m0 = m_t * 128 + wr * 64, n0 = n_t * 128 + wc * 64;
#pragma unroll
    for (int nt = 0; nt < 4; ++nt) {
      int col = n0 + nt * 16 + fr;
      float bval = bv[col];
      int h = col >> 6, d = col & 63;
#pragma unroll
      for (int mt = 0; mt < 4; ++mt) {
        int rowb = m0 + mt * 16 + hi2 * 4;
        int b = rowb >> 9, t = rowb & 511;
        size_t idx =
            ((size_t)((b * 8 + h) * 4 + (d >> 4)) * 16 + (t >> 5)) * 512 +
            ((t & 31) >> 3) * 128 + (d & 15) * 8 + (t & 7);
        u16x4 hv;
#pragma unroll
        for (int r = 0; r < 4; ++r) hv[r] = f2bf(acc[mt][nt][r] + bval);
        *(u16x4*)(vth + idx) = hv;
      }
    }
  }
}

__global__ __launch_bounds__(256) void out_gemm(
    const unsigned short* __restrict__ ctxpk, const unsigned short* __restrict__ wom,
    const float* __restrict__ bo, float* __restrict__ out) {
  __shared__ __align__(16) unsigned short lA[8192];
  __shared__ __align__(16) unsigned short lB[8192];
  const int tid = threadIdx.x, lane = tid & 63, wave = tid >> 6;
  const int bid = blockIdx.x;  // 256 blocks: 64 m x 4 n (128x128 tiles)
  const int wr = wave >> 1, wc = wave & 1;
  const int fr = lane & 15, hi2 = lane >> 4;
  int m_t = bid >> 2, n_t = bid & 3;
  f32x4 fz = {0.f, 0.f, 0.f, 0.f};
  f32x4 acc[4][4];
#pragma unroll
  for (int i = 0; i < 4; i++)
#pragma unroll
    for (int j = 0; j < 4; j++) acc[i][j] = fz;
  gemm128_db<true>(ctxpk, m_t * 8, wom, n_t * 8, lA, lB, wave, lane, acc);
  int m0 = m_t * 128 + wr * 64, n0 = n_t * 128 + wc * 64;
#pragma unroll
  for (int nt = 0; nt < 4; ++nt) {
    int colb = n0 + nt * 16 + hi2 * 4;
    float4 b4 = *(const float4*)(bo + colb);
#pragma unroll
    for (int mt = 0; mt < 4; ++mt) {
      int row = m0 + mt * 16 + fr;
      float4 o;
      o.x = acc[mt][nt][0] + b4.x;
      o.y = acc[mt][nt][1] + b4.y;
      o.z = acc[mt][nt][2] + b4.z;
      o.w = acc[mt][nt][3] + b4.w;
      *(float4*)(out + (size_t)row * 512 + colb) = o;
    }
  }
}

// ---------------- flash attention, LDS-staged K/P/V pipeline ---------------
// grid 1024; id%128=(b,h), id>>7=s_blk. Block = 4 waves x 16 q-rows.
// K,V: wave-invariant -> double-buffered LDS (staged 1x/block instead of 4x).
// P: block union = 6 consecutive tiles, 2 new per step -> 8-slot LDS ring.
// pbase(s) = 31 - 4*s_blk + 2*s; wave w reads tiles pbase-w..pbase-w+2.
// Stage-ahead: issue stage(s+1) before compute(s); 1 barrier/step. Fragments
// ds_read_b128 from an LDS image byte-identical to the packed global layout.
__global__ __launch_bounds__(256) void flash_attn(
    const unsigned short* __restrict__ qc, const unsigned short* __restrict__ qp,
    const unsigned short* __restrict__ kb, const unsigned short* __restrict__ pm,
    const unsigned short* __restrict__ vth, unsigned short* __restrict__ ctxpk) {
  const int id = blockIdx.x;
  const int bh = id & 127, b = bh >> 3, h = bh & 7;
  const int s_blk = id >> 7;
  const int tid = threadIdx.x, wave = tid >> 6, lane = tid & 63;
  const int fr = lane & 15, hi2 = lane >> 4, fc = hi2 * 8;
  const int s0w = s_blk * 64 + wave * 16;
  const int crow = hi2 * 4;
  const int pbase0 = 31 - 4 * s_blk;  // P tile base at step 0 for wave 0

  __shared__ __align__(16) unsigned short lK[4096];  // 2 bufs x 2 tiles x 1024
  __shared__ __align__(16) unsigned short lV[4096];  // 2 bufs x 4 x 512
  __shared__ __align__(16) unsigned short lP[8192];  // 8-slot ring x 1024
  __shared__ __align__(16) unsigned short Ph_s[4][16][40];
  unsigned short(*Phw)[40] = Ph_s[wave];

  int srcl[4];
#pragma unroll
  for (int r = 0; r < 4; ++r) srcl[r] = (hi2 << 4) | ((fr - (crow + r) - 1) & 15);

  const size_t qtb = ((size_t)(b * 8 + h) * 32 + (s0w >> 4)) * 1024 + lane * 8;
  s16x8 aqc0 = *(const s16x8*)(qc + qtb);
  s16x8 aqc1 = *(const s16x8*)(qc + qtb + 512);
  s16x8 aqp0 = *(const s16x8*)(qp + qtb);
  s16x8 aqp1 = *(const s16x8*)(qp + qtb + 512);

  // per-lane global srcs (include lane*8 = 16B/lane for gload_lds16)
  const unsigned short* kpk = kb + (size_t)(b * 8 + h) * 32768 + lane * 8;
  const unsigned short* ppk = pm + (size_t)(b * 8 + h) * 65536 + lane * 8;
  const unsigned short* vhk = vth + (size_t)(b * 8 + h) * 32768 + lane * 8;

  // ---- prologue stage: K(0), V(0), P tiles [pbase0-3 .. pbase0+2] ----
  if (wave == 0) {
#pragma unroll
    for (int c = 0; c < 4; ++c) gload_lds16(kpk + c * 512, lK + c * 512);
  } else if (wave == 1) {
#pragma unroll
    for (int c = 0; c < 4; ++c)
      gload_lds16(vhk + (size_t)(c * 16) * 512, lV + c * 512);
  } else {
#pragma unroll
    for (int j = 0; j < 3; ++j) {
      const int t = pbase0 - 3 + (wave - 2) * 3 + j;  // w2: -3..-1, w3: 0..+2
#pragma unroll
      for (int hf = 0; hf < 2; ++hf)
        gload_lds16(ppk + (size_t)t * 1024 + hf * 512,
                    lP + (t & 7) * 1024 + hf * 512);
    }
  }

  f32x4 fz = {0.f, 0.f, 0.f, 0.f};
  f32x4 Oacc[4] = {fz, fz, fz, fz};
  float lsum[4] = {0.f, 0.f, 0.f, 0.f};

  __syncthreads();  // prologue staged

#pragma unroll 2
  for (int s = 0; s < 16; ++s) {
    const int cur = s & 1, nxt = cur ^ 1;
    // ---- stage-ahead for step s+1 ----
    if (s < 15) {
      const int sn = s + 1;
      if (wave == 0) {  // K(sn): tiles 2sn, 2sn+1
#pragma unroll
        for (int c = 0; c < 4; ++c)
          gload_lds16(kpk + (size_t)(2 * sn) * 1024 + c * 512,
                      lK + nxt * 2048 + c * 512);
      } else if (wave == 1) {  // V(sn)
#pragma unroll
        for (int c = 0; c < 4; ++c)
          gload_lds16(vhk + (size_t)(c * 16 + sn) * 512,
                      lV + nxt * 2048 + c * 512);
      } else {  // P: new tiles pbase(s)+3, pbase(s)+4
        const int t = pbase0 + 2 * s + 3 + (wave - 2);
#pragma unroll
        for (int hf = 0; hf < 2; ++hf)
          gload_lds16(ppk + (size_t)t * 1024 + hf * 512,
                      lP + (t & 7) * 1024 + hf * 512);
      }
    }
    // ---- fragments from LDS ----
    const unsigned short* lk = lK + cur * 2048 + lane * 8;
    const unsigned short* lv = lV + cur * 2048 + lane * 8;
    s16x8 kf[4], pf[6], vf[4];
#pragma unroll
    for (int nt = 0; nt < 2; ++nt) {
      kf[2 * nt] = *(const s16x8*)(lk + nt * 1024);
      kf[2 * nt + 1] = *(const s16x8*)(lk + nt * 1024 + 512);
    }
#pragma unroll
    for (int nt = 0; nt < 3; ++nt) {
      const int t = pbase0 + 2 * s - wave + nt;
      const unsigned short* lp = lP + (t & 7) * 1024 + lane * 8;
      pf[2 * nt] = *(const s16x8*)lp;
      pf[2 * nt + 1] = *(const s16x8*)(lp + 512);
    }
#pragma unroll
    for (int nt = 0; nt < 4; ++nt) vf[nt] = *(const s16x8*)(lv + nt * 512);

    // ---- QK^T + pos MFMA ----
    f32x4 sc[2] = {fz, fz};
    __builtin_amdgcn_s_setprio(1);
#pragma unroll
    for (int nt = 0; nt < 2; ++nt) {
      sc[nt] = __builtin_amdgcn_mfma_f32_16x16x32_bf16(aqc0, kf[2 * nt],
                                                       sc[nt], 0, 0, 0);
      sc[nt] = __builtin_amdgcn_mfma_f32_16x16x32_bf16(aqc1, kf[2 * nt + 1],
                                                       sc[nt], 0, 0, 0);
    }
    f32x4 sp[3];
#pragma unroll
    for (int nt = 0; nt < 3; ++nt) {
      f32x4 t2 = fz;
      t2 = __builtin_amdgcn_mfma_f32_16x16x32_bf16(aqp0, pf[2 * nt], t2, 0, 0, 0);
      t2 = __builtin_amdgcn_mfma_f32_16x16x32_bf16(aqp1, pf[2 * nt + 1], t2, 0, 0, 0);
      sp[nt] = t2;
    }
    __builtin_amdgcn_s_setprio(0);
    // ---- rel-shift gather + softmax ----
    float sj[3][4];
#pragma unroll
    for (int j = 0; j < 3; ++j)
#pragma unroll
      for (int r = 0; r < 4; ++r) sj[j][r] = __shfl(sp[j][r], srcl[r], 64);
#pragma unroll
    for (int nt = 0; nt < 2; ++nt) {
      int tc = nt * 16 + fr;
#pragma unroll
      for (int r = 0; r < 4; ++r) {
        float pos = (fr <= crow + r) ? sj[nt][r] : sj[nt + 1][r];
        float e = EXP2(sc[nt][r] + pos);
        lsum[r] += e;
        Phw[crow + r][tc] = f2bf(e);
      }
    }
    s16x8 ah = *(const s16x8*)&Phw[fr][fc];
    __builtin_amdgcn_s_setprio(1);
#pragma unroll
    for (int nt = 0; nt < 4; ++nt)
      Oacc[nt] = __builtin_amdgcn_mfma_f32_16x16x32_bf16(ah, vf[nt], Oacc[nt],
                                                         0, 0, 0);
    __builtin_amdgcn_s_setprio(0);
    __syncthreads();  // staged(s+1) landed; buffers for s fully consumed
  }

#pragma unroll
  for (int d = 1; d < 16; d <<= 1)
#pragma unroll
    for (int r = 0; r < 4; ++r) lsum[r] += __shfl_xor(lsum[r], d, 64);
  // epilogue: ctx in packed A-fragment layout for the out GEMM
#pragma unroll
  for (int nt = 0; nt < 4; ++nt)
#pragma unroll
    for (int r = 0; r < 4; ++r) {
      float o = Oacc[nt][r] / lsum[r];
      int row = b * 512 + s0w + crow + r;
      int col = h * 64 + nt * 16 + fr;
      ctxpk[pk(row, col)] = f2bf(o);
    }
}

// ---------------------------------------------------------------------------
extern "C" void kernel_launch(void* const* d_in, const int* in_sizes, int n_in,
                              void* d_out, int out_size, void* d_ws,
                              size_t ws_size, hipStream_t stream) {
  const float* x = (const float*)d_in[0];
  const float* pe = (const float*)d_in[1];
  const float* ln_g = (const float*)d_in[2];
  const float* ln_b = (const float*)d_in[3];
  const float* Wq = (const float*)d_in[4];
  const float* bq = (const float*)d_in[5];
  const float* Wk = (const float*)d_in[6];
  const float* bk = (const float*)d_in[7];
  const float* Wv = (const float*)d_in[8];
  const float* bv = (const float*)d_in[9];
  const float* Wp = (const float*)d_in[10];
  const float* bp = (const float*)d_in[11];
  const float* cb = (const float*)d_in[12];
  const float* pb = (const float*)d_in[13];
  const float* Wo = (const float*)d_in[14];
  const float* bo = (const float*)d_in[15];
  float* out = (float*)d_out;

  char* ws = (char*)d_ws;
  size_t off = 0;
  auto alloc = [&](size_t bytes) -> char* {
    char* ptr = ws + off;
    off = (off + bytes + 255) & ~(size_t)255;
    return ptr;
  };
  // xn packed (8.4 MB) -> reused as ctx packed after proj_all completes
  unsigned short* xpk = (unsigned short*)alloc((size_t)8192 * 512 * 2);
  unsigned short* ctxpk = xpk;
  unsigned short* pepk = (unsigned short*)alloc((size_t)16384 * 512 * 2);
  unsigned short* vt_hi = (unsigned short*)alloc((size_t)8192 * 512 * 2);
  unsigned short* wqk = (unsigned short*)alloc((size_t)1024 * 512 * 2);
  unsigned short* wpm = (unsigned short*)alloc((size_t)512 * 512 * 2);
  unsigned short* wvm = (unsigned short*)alloc((size_t)512 * 512 * 2);
  unsigned short* wom = (unsigned short*)alloc((size_t)512 * 512 * 2);
  float* bqk = (float*)alloc(1024 * 4);
  unsigned short* qc = (unsigned short*)alloc((size_t)8192 * 512 * 2);
  unsigned short* qp = (unsigned short*)alloc((size_t)8192 * 512 * 2);
  unsigned short* kbuf = (unsigned short*)alloc((size_t)8192 * 512 * 2);
  unsigned short* pbuf = (unsigned short*)alloc((size_t)16384 * 512 * 2);

  if (ws_size < off) {
    fprintf(stderr, "kernel_launch: ws too small (need %zu, have %zu)\n", off,
            ws_size);
    return;
  }

  megaprep<<<6784, 256, 0, stream>>>(x, ln_g, ln_b, xpk, pe, pepk, Wq, Wk, Wp,
                                     Wv, Wo, bq, bk, wqk, wpm, wvm, wom, bqk);
  proj_all<<<1280, 256, 0, stream>>>(xpk, pepk, wqk, wpm, wvm, bqk, bp, bv,
                                     cb, pb, qc, qp, kbuf, pbuf, vt_hi);
  flash_attn<<<1024, 256, 0, stream>>>(qc, qp, kbuf, pbuf, vt_hi, ctxpk);
  out_gemm<<<256, 256, 0, stream>>>(ctxpk, wom, bo, out);
}

// Round 8
// 205.814 us; speedup vs baseline: 1.0555x; 1.0555x over previous
//
#include <hip/hip_runtime.h>
#include <cstdio>
#include <cstdint>

// ---------------------------------------------------------------------------
// Transformer-XL relative MHA, MI355X/gfx950.  B=16 T=512 D=512 H=8 hd=64.
// Round 19: counted-vmcnt pipeline for proj/out GEMMs. R18 proved the
// invariant bottleneck: every prior structure drains vmcnt to 0 at each
// barrier (__syncthreads), exposing full load latency per K-step (and
// occupancy never moved with LDS size -> not residency-bound). Fix = T4:
// 3-buffer, stage-TWO-ahead, raw s_barrier + literal s_waitcnt vmcnt(N),
// never 0 in the loop: {STG(t+2); vmcnt(8); bar; ds_read+16 MFMA; bar}.
// Batch t+2 stays in flight across 2 compute windows (~800cy cover).
// Race audit: STG(t+2) writes buf[(t-1)%3], retired by barrier2(t-1) for
// ALL waves; batch-t cross-wave visibility = own vmcnt(8) before barrier1.
// Tail: t=14 vmcnt(4), t=15 vmcnt(0). LDS 48KB -> 3 blocks/CU. Same kc
// order -> bit-identical numerics. flash_attn/megaprep = R17/R18.
// pack(r,k) = (r>>4)*8192 + (k>>5)*512 + ((k>>3)&3)*128 + (r&15)*8 + (k&7)
// ---------------------------------------------------------------------------

typedef short s16x8 __attribute__((ext_vector_type(8)));
typedef float f32x4 __attribute__((ext_vector_type(4)));
typedef unsigned short u16x4 __attribute__((ext_vector_type(4)));
typedef unsigned short u16x8 __attribute__((ext_vector_type(8)));

#define CSCALE 0.1803368801111204f  // log2(e)/8

#if __has_builtin(__builtin_amdgcn_exp2f)
#define EXP2(x) __builtin_amdgcn_exp2f(x)
#else
#define EXP2(x) exp2f(x)
#endif

__device__ __forceinline__ unsigned short f2bf(float f) {  // RNE
  unsigned int u = __builtin_bit_cast(unsigned int, f);
  unsigned int r = (u + 0x7FFFu + ((u >> 16) & 1u)) >> 16;
  return (unsigned short)r;
}
__device__ __forceinline__ float bf2f(unsigned short h) {
  unsigned int u = ((unsigned int)h) << 16;
  return __builtin_bit_cast(float, u);
}
// fragment-strip packing: strips of 16 rows x 512 k (8192 shorts)
__device__ __forceinline__ size_t pk(int row, int col) {
  return (size_t)(row >> 4) * 8192 + (col >> 5) * 512 + ((col >> 3) & 3) * 128 +
         (row & 15) * 8 + (col & 7);
}

// async global->LDS, 16B per lane. Global src is PER-LANE; LDS dst is the
// wave-uniform base (HW adds lane*16).
__device__ __forceinline__ void gload_lds16(const unsigned short* g,
                                            unsigned short* l) {
  __builtin_amdgcn_global_load_lds(
      (const __attribute__((address_space(1))) unsigned int*)g,
      (__attribute__((address_space(3))) unsigned int*)l, 16, 0, 0);
}

// ---------------- fused prep (vectorized stores) ---------------------------
__global__ __launch_bounds__(256) void megaprep(
    const float* __restrict__ x, const float* __restrict__ g,
    const float* __restrict__ bb, unsigned short* __restrict__ xpk,
    const float* __restrict__ pe, unsigned short* __restrict__ pepk,
    const float* __restrict__ Wq, const float* __restrict__ Wk,
    const float* __restrict__ Wp, const float* __restrict__ Wv,
    const float* __restrict__ Wo, const float* __restrict__ bq,
    const float* __restrict__ bk, unsigned short* __restrict__ wqk,
    unsigned short* __restrict__ wpm, unsigned short* __restrict__ wvm,
    unsigned short* __restrict__ wom, float* __restrict__ bqk) {
  const int bid = blockIdx.x, tid = threadIdx.x;
  if (bid < 2048) {  // LN: row = bid*4 + wave
    const int wave = tid >> 6, lane = tid & 63;
    const int row = bid * 4 + wave;
    const int c0 = lane * 8;
    const float* xr = x + (size_t)row * 512 + c0;
    float4 v0 = *(const float4*)xr;
    float4 v1 = *(const float4*)(xr + 4);
    float vv[8] = {v0.x, v0.y, v0.z, v0.w, v1.x, v1.y, v1.z, v1.w};
    float s = 0.f, ss = 0.f;
#pragma unroll
    for (int j = 0; j < 8; ++j) { s += vv[j]; ss += vv[j] * vv[j]; }
#pragma unroll
    for (int d = 1; d < 64; d <<= 1) {
      s += __shfl_xor(s, d, 64);
      ss += __shfl_xor(ss, d, 64);
    }
    const float mu = s * (1.0f / 512.0f);
    const float var = ss * (1.0f / 512.0f) - mu * mu;
    const float rstd = rsqrtf(var + 1e-5f);
    u16x8 o;
#pragma unroll
    for (int j = 0; j < 8; ++j)
      o[j] = f2bf((vv[j] - mu) * rstd * g[c0 + j] + bb[c0 + j]);
    *(u16x8*)(xpk + pk(row, c0)) = o;
  } else if (bid < 6144) {  // pe: 8 elems/thread
    int gid = (bid - 2048) * 256 + tid;
    int e = gid * 8;  // over 16384*512
    int r = e >> 9, c = e & 511;
    int b = r >> 10, u = r & 1023;
    u16x8 o = {0, 0, 0, 0, 0, 0, 0, 0};
    if (u < 1023) {
      const float* src = pe + (size_t)(b * 1023 + u) * 512 + c;
      float4 v0 = *(const float4*)src;
      float4 v1 = *(const float4*)(src + 4);
      o[0] = f2bf(v0.x); o[1] = f2bf(v0.y); o[2] = f2bf(v0.z); o[3] = f2bf(v0.w);
      o[4] = f2bf(v1.x); o[5] = f2bf(v1.y); o[6] = f2bf(v1.z); o[7] = f2bf(v1.w);
    }
    *(u16x8*)(pepk + (size_t)b * 524288 + pk(u, c)) = o;
  } else {  // weights: 8 elems/thread
    int gid = (bid - 6144) * 256 + tid;
    int idx = gid * 8;  // over 5*262144
    int region = idx >> 18, off = idx & 262143;
    const float* src = (region == 0)   ? Wq
                       : (region == 1) ? Wk
                       : (region == 2) ? Wp
                       : (region == 3) ? Wv
                                       : Wo;
    float4 v0 = *(const float4*)(src + off);
    float4 v1 = *(const float4*)(src + off + 4);
    u16x8 o;
    o[0] = f2bf(v0.x); o[1] = f2bf(v0.y); o[2] = f2bf(v0.z); o[3] = f2bf(v0.w);
    o[4] = f2bf(v1.x); o[5] = f2bf(v1.y); o[6] = f2bf(v1.z); o[7] = f2bf(v1.w);
    int n = off >> 9, k = off & 511;
    unsigned short* dst;
    int nrow = n;
    if (region == 0) { dst = wqk; }
    else if (region == 1) { dst = wqk; nrow = n + 512; }
    else if (region == 2) { dst = wpm; }
    else if (region == 3) { dst = wvm; }
    else { dst = wom; }
    *(u16x8*)(dst + pk(nrow, k)) = o;
    if (idx < 1024) {
#pragma unroll
      for (int j = 0; j < 8; j++) {
        int ii = idx + j;
        bqk[ii] = (ii < 512) ? bq[ii] : bk[ii - 512];
      }
    }
  }
}

// ---------------- 128x128 GEMM core: 3-buf, stage-2-ahead, counted vmcnt ---
// 4 waves, each a 64x64 quadrant. K=512 in 16 steps of BK=32. LDS:
// 3 x (8KB A + 8KB B) = 48KB -> 3 blocks/CU. Per step t:
//   STG(t+2 -> buf[(t+2)%3])      (4 gload_lds16/wave; writes buf retired
//                                  by barrier2(t-1) for ALL waves)
//   s_waitcnt vmcnt(8)            (own batch-t landed; t+1,t+2 stay in
//                                  flight ACROSS the barrier - T4)
//   s_barrier                     (cross-wave: everyone's batch-t visible)
//   8 ds_read_b128 + 16 MFMA on buf[t%3]
//   s_barrier                     (buf[t%3] retired -> STG(t+3) may overwrite)
// Tail: t=14 vmcnt(4), t=15 vmcnt(0). No vmcnt(0) in steady state.
template <bool SWAP>
__device__ __forceinline__ void gemm128_p3(
    const unsigned short* __restrict__ Apk, int astrip8,
    const unsigned short* __restrict__ Bpk, int bstrip8,
    unsigned short* __restrict__ lA, unsigned short* __restrict__ lB,
    int wave, int lane, f32x4 acc[4][4]) {
  const int wr = wave >> 1, wc = wave & 1;
  const unsigned short* ga =
      Apk + (size_t)(astrip8 + 2 * wave) * 8192 + lane * 8;
  const unsigned short* gb =
      Bpk + (size_t)(bstrip8 + 2 * wave) * 8192 + lane * 8;
  // stage 32-k chunk kc (512 shorts/strip, contiguous) of strips {2w,2w+1}
#define STG3(kc, buf)                                                        \
  _Pragma("unroll") for (int s = 0; s < 2; ++s) {                            \
    gload_lds16(ga + (size_t)s * 8192 + (kc) * 512,                          \
                lA + (buf) * 4096 + (2 * wave + s) * 512);                   \
    gload_lds16(gb + (size_t)s * 8192 + (kc) * 512,                          \
                lB + (buf) * 4096 + (2 * wave + s) * 512);                   \
  }
  STG3(0, 0);
  STG3(1, 1);
  const unsigned short* lar = lA + (wr * 4) * 512 + lane * 8;
  const unsigned short* lbr = lB + (wc * 4) * 512 + lane * 8;
#pragma unroll
  for (int kc = 0; kc < 16; ++kc) {
    const int cur = kc % 3;
    if (kc < 14) { STG3(kc + 2, (kc + 2) % 3); }
    // wait for OWN batch kc (oldest); later batches stay in flight
    if (kc < 14) {
      asm volatile("s_waitcnt vmcnt(8)" ::: "memory");
    } else if (kc == 14) {
      asm volatile("s_waitcnt vmcnt(4)" ::: "memory");
    } else {
      asm volatile("s_waitcnt vmcnt(0)" ::: "memory");
    }
    __builtin_amdgcn_s_barrier();          // batch kc visible block-wide
    __builtin_amdgcn_sched_barrier(0);     // pin: no hoist across barrier
    s16x8 af[4], bf[4];
#pragma unroll
    for (int mt = 0; mt < 4; ++mt)
      af[mt] = *(const s16x8*)(lar + cur * 4096 + mt * 512);
#pragma unroll
    for (int nt = 0; nt < 4; ++nt)
      bf[nt] = *(const s16x8*)(lbr + cur * 4096 + nt * 512);
#pragma unroll
    for (int mt = 0; mt < 4; ++mt)
#pragma unroll
      for (int nt = 0; nt < 4; ++nt)
        acc[mt][nt] =
            SWAP ? __builtin_amdgcn_mfma_f32_16x16x32_bf16(
                       bf[nt], af[mt], acc[mt][nt], 0, 0, 0)
                 : __builtin_amdgcn_mfma_f32_16x16x32_bf16(
                       af[mt], bf[nt], acc[mt][nt], 0, 0, 0);
    __builtin_amdgcn_sched_barrier(0);     // keep reads inside the window
    __builtin_amdgcn_s_barrier();          // buf[kc%3] retired
  }
#undef STG3
}

// merged projections: 128x128 block tiles.
__global__ __launch_bounds__(256) void proj_all(
    const unsigned short* __restrict__ xpk, const unsigned short* __restrict__ pepk,
    const unsigned short* __restrict__ wqk, const unsigned short* __restrict__ wpm,
    const unsigned short* __restrict__ wvm, const float* __restrict__ bqk,
    const float* __restrict__ bp, const float* __restrict__ bv,
    const float* __restrict__ cbv, const float* __restrict__ pbv,
    unsigned short* __restrict__ qc, unsigned short* __restrict__ qp,
    unsigned short* __restrict__ kb, unsigned short* __restrict__ pbuf,
    unsigned short* __restrict__ vth) {
  __shared__ __align__(16) unsigned short lA[12288];  // 3 x 8KB
  __shared__ __align__(16) unsigned short lB[12288];
  const int tid = threadIdx.x, lane = tid & 63, wave = tid >> 6;
  int bid = blockIdx.x;
  bid = (bid & 7) * 160 + (bid >> 3);  // XCD swizzle (1280 % 8 == 0)
  const int wr = wave >> 1, wc = wave & 1;
  const int fr = lane & 15, hi2 = lane >> 4;
  f32x4 fz = {0.f, 0.f, 0.f, 0.f};
  f32x4 acc[4][4];
#pragma unroll
  for (int i = 0; i < 4; i++)
#pragma unroll
    for (int j = 0; j < 4; j++) acc[i][j] = fz;

  if (bid < 512) {  // qk (swapped)
    int m_t = bid >> 3, n_t = bid & 7;
    gemm128_p3<true>(xpk, m_t * 8, wqk, n_t * 8, lA, lB, wave, lane, acc);
    int m0 = m_t * 128 + wr * 64, n0 = n_t * 128 + wc * 64;
#pragma unroll
    for (int nt = 0; nt < 4; ++nt) {
      int colb = n0 + nt * 16 + hi2 * 4;
      float4 b4 = *(const float4*)(bqk + colb);
      float bvv[4] = {b4.x, b4.y, b4.z, b4.w};
      if (colb < 512) {  // -> qc/qp
        int h = colb >> 6, cc = colb & 63;
        float4 c4 = *(const float4*)(cbv + colb);
        float4 p4 = *(const float4*)(pbv + colb);
        float cvv[4] = {c4.x, c4.y, c4.z, c4.w};
        float pvv[4] = {p4.x, p4.y, p4.z, p4.w};
        size_t cpart = (size_t)(cc >> 5) * 512 + ((cc & 31) >> 3) * 128 +
                       (cc & 7) + (size_t)h * 32768;
#pragma unroll
        for (int mt = 0; mt < 4; ++mt) {
          int row = m0 + mt * 16 + fr;
          int b = row >> 9, s16i = (row & 511) >> 4;
          size_t idx = ((size_t)b * 8 * 32 + s16i) * 1024 + cpart + fr * 8;
          u16x4 oc, op;
#pragma unroll
          for (int r = 0; r < 4; ++r) {
            float val = acc[mt][nt][r] + bvv[r];
            oc[r] = f2bf((val + cvv[r]) * CSCALE);
            op[r] = f2bf((val + pvv[r]) * CSCALE);
          }
          *(u16x4*)(qc + idx) = oc;
          *(u16x4*)(qp + idx) = op;
        }
      } else {  // -> kb
        int c2 = colb - 512, h = c2 >> 6, cc = c2 & 63;
        size_t cpart = (size_t)(cc >> 5) * 512 + ((cc & 31) >> 3) * 128 +
                       (cc & 7) + (size_t)h * 32768;
#pragma unroll
        for (int mt = 0; mt < 4; ++mt) {
          int row = m0 + mt * 16 + fr;
          int b = row >> 9, s16i = (row & 511) >> 4;
          size_t idx = ((size_t)b * 8 * 32 + s16i) * 1024 + cpart + fr * 8;
          u16x4 ok;
#pragma unroll
          for (int r = 0; r < 4; ++r) ok[r] = f2bf(acc[mt][nt][r] + bvv[r]);
          *(u16x4*)(kb + idx) = ok;
        }
      }
    }
  } else if (bid < 1024) {  // p (per-b packed A, swapped)
    int pid = bid - 512;
    int b = pid >> 5, rem = pid & 31;
    int m_tb = rem >> 2, n_t = rem & 3;
    gemm128_p3<true>(pepk + (size_t)b * 524288, m_tb * 8, wpm, n_t * 8, lA,
                     lB, wave, lane, acc);
    int u0 = m_tb * 128 + wr * 64, n0 = n_t * 128 + wc * 64;
#pragma unroll
    for (int nt = 0; nt < 4; ++nt) {
      int colb = n0 + nt * 16 + hi2 * 4;
      float4 b4 = *(const float4*)(bp + colb);
      float bvv[4] = {b4.x, b4.y, b4.z, b4.w};
      int h = colb >> 6, cc = colb & 63;
      size_t cbase = (size_t)(b * 8 + h) * 65536 + (cc >> 5) * 512 +
                     ((cc & 31) >> 3) * 128 + (cc & 7);
#pragma unroll
      for (int mt = 0; mt < 4; ++mt) {
        int u = u0 + mt * 16 + fr;
        size_t idx = cbase + (size_t)(u >> 4) * 1024 + (u & 15) * 8;
        u16x4 o;
        if (u >= 1023) {
          o[0] = 0; o[1] = 0; o[2] = 0; o[3] = 0;
        } else {
#pragma unroll
          for (int r = 0; r < 4; ++r) o[r] = f2bf(acc[mt][nt][r] + bvv[r]);
        }
        *(u16x4*)(pbuf + idx) = o;
      }
    }
  } else {  // v -> vT packed (NOT swapped)
    int vid = bid - 1024;
    int m_t = vid >> 2, n_t = vid & 3;
    gemm128_p3<false>(xpk, m_t * 8, wvm, n_t * 8, lA, lB, wave, lane, acc);
    int m0 = m_t * 128 + wr * 64, n0 = n_t * 128 + wc * 64;
#pragma unroll
    for (int nt = 0; nt < 4; ++nt) {
      int col = n0 + nt * 16 + fr;
      float bval = bv[col];
      int h = col >> 6, d = col & 63;
#pragma unroll
      for (int mt = 0; mt < 4; ++mt) {
        int rowb = m0 + mt * 16 + hi2 * 4;
        int b = rowb >> 9, t = rowb & 511;
        size_t idx =
            ((size_t)((b * 8 + h) * 4 + (d >> 4)) * 16 + (t >> 5)) * 512 +
            ((t & 31) >> 3) * 128 + (d & 15) * 8 + (t & 7);
        u16x4 hv;
#pragma unroll
        for (int r = 0; r < 4; ++r) hv[r] = f2bf(acc[mt][nt][r] + bval);
        *(u16x4*)(vth + idx) = hv;
      }
    }
  }
}

__global__ __launch_bounds__(256) void out_gemm(
    const unsigned short* __restrict__ ctxpk, const unsigned short* __restrict__ wom,
    const float* __restrict__ bo, float* __restrict__ out) {
  __shared__ __align__(16) unsigned short lA[12288];
  __shared__ __align__(16) unsigned short lB[12288];
  const int tid = threadIdx.x, lane = tid & 63, wave = tid >> 6;
  const int bid = blockIdx.x;  // 256 blocks: 64 m x 4 n (128x128 tiles)
  const int wr = wave >> 1, wc = wave & 1;
  const int fr = lane & 15, hi2 = lane >> 4;
  int m_t = bid >> 2, n_t = bid & 3;
  f32x4 fz = {0.f, 0.f, 0.f, 0.f};
  f32x4 acc[4][4];
#pragma unroll
  for (int i = 0; i < 4; i++)
#pragma unroll
    for (int j = 0; j < 4; j++) acc[i][j] = fz;
  gemm128_p3<true>(ctxpk, m_t * 8, wom, n_t * 8, lA, lB, wave, lane, acc);
  int m0 = m_t * 128 + wr * 64, n0 = n_t * 128 + wc * 64;
#pragma unroll
  for (int nt = 0; nt < 4; ++nt) {
    int colb = n0 + nt * 16 + hi2 * 4;
    float4 b4 = *(const float4*)(bo + colb);
#pragma unroll
    for (int mt = 0; mt < 4; ++mt) {
      int row = m0 + mt * 16 + fr;
      float4 o;
      o.x = acc[mt][nt][0] + b4.x;
      o.y = acc[mt][nt][1] + b4.y;
      o.z = acc[mt][nt][2] + b4.z;
      o.w = acc[mt][nt][3] + b4.w;
      *(float4*)(out + (size_t)row * 512 + colb) = o;
    }
  }
}

// ---------------- flash attention, LDS-staged K/P/V pipeline ---------------
// grid 1024; id%128=(b,h), id>>7=s_blk. Block = 4 waves x 16 q-rows.
// K,V: wave-invariant -> double-buffered LDS (staged 1x/block instead of 4x).
// P: block union = 6 consecutive tiles, 2 new per step -> 8-slot LDS ring.
// pbase(s) = 31 - 4*s_blk + 2*s; wave w reads tiles pbase-w..pbase-w+2.
// Stage-ahead: issue stage(s+1) before compute(s); 1 barrier/step. Fragments
// ds_read_b128 from an LDS image byte-identical to the packed global layout.
__global__ __launch_bounds__(256) void flash_attn(
    const unsigned short* __restrict__ qc, const unsigned short* __restrict__ qp,
    const unsigned short* __restrict__ kb, const unsigned short* __restrict__ pm,
    const unsigned short* __restrict__ vth, unsigned short* __restrict__ ctxpk) {
  const int id = blockIdx.x;
  const int bh = id & 127, b = bh >> 3, h = bh & 7;
  const int s_blk = id >> 7;
  const int tid = threadIdx.x, wave = tid >> 6, lane = tid & 63;
  const int fr = lane & 15, hi2 = lane >> 4, fc = hi2 * 8;
  const int s0w = s_blk * 64 + wave * 16;
  const int crow = hi2 * 4;
  const int pbase0 = 31 - 4 * s_blk;  // P tile base at step 0 for wave 0

  __shared__ __align__(16) unsigned short lK[4096];  // 2 bufs x 2 tiles x 1024
  __shared__ __align__(16) unsigned short lV[4096];  // 2 bufs x 4 x 512
  __shared__ __align__(16) unsigned short lP[8192];  // 8-slot ring x 1024
  __shared__ __align__(16) unsigned short Ph_s[4][16][40];
  unsigned short(*Phw)[40] = Ph_s[wave];

  int srcl[4];
#pragma unroll
  for (int r = 0; r < 4; ++r) srcl[r] = (hi2 << 4) | ((fr - (crow + r) - 1) & 15);

  const size_t qtb = ((size_t)(b * 8 + h) * 32 + (s0w >> 4)) * 1024 + lane * 8;
  s16x8 aqc0 = *(const s16x8*)(qc + qtb);
  s16x8 aqc1 = *(const s16x8*)(qc + qtb + 512);
  s16x8 aqp0 = *(const s16x8*)(qp + qtb);
  s16x8 aqp1 = *(const s16x8*)(qp + qtb + 512);

  // per-lane global srcs (include lane*8 = 16B/lane for gload_lds16)
  const unsigned short* kpk = kb + (size_t)(b * 8 + h) * 32768 + lane * 8;
  const unsigned short* ppk = pm + (size_t)(b * 8 + h) * 65536 + lane * 8;
  const unsigned short* vhk = vth + (size_t)(b * 8 + h) * 32768 + lane * 8;

  // ---- prologue stage: K(0), V(0), P tiles [pbase0-3 .. pbase0+2] ----
  if (wave == 0) {
#pragma unroll
    for (int c = 0; c < 4; ++c) gload_lds16(kpk + c * 512, lK + c * 512);
  } else if (wave == 1) {
#pragma unroll
    for (int c = 0; c < 4; ++c)
      gload_lds16(vhk + (size_t)(c * 16) * 512, lV + c * 512);
  } else {
#pragma unroll
    for (int j = 0; j < 3; ++j) {
      const int t = pbase0 - 3 + (wave - 2) * 3 + j;  // w2: -3..-1, w3: 0..+2
#pragma unroll
      for (int hf = 0; hf < 2; ++hf)
        gload_lds16(ppk + (size_t)t * 1024 + hf * 512,
                    lP + (t & 7) * 1024 + hf * 512);
    }
  }

  f32x4 fz = {0.f, 0.f, 0.f, 0.f};
  f32x4 Oacc[4] = {fz, fz, fz, fz};
  float lsum[4] = {0.f, 0.f, 0.f, 0.f};

  __syncthreads();  // prologue staged

#pragma unroll 2
  for (int s = 0; s < 16; ++s) {
    const int cur = s & 1, nxt = cur ^ 1;
    // ---- stage-ahead for step s+1 ----
    if (s < 15) {
      const int sn = s + 1;
      if (wave == 0) {  // K(sn): tiles 2sn, 2sn+1
#pragma unroll
        for (int c = 0; c < 4; ++c)
          gload_lds16(kpk + (size_t)(2 * sn) * 1024 + c * 512,
                      lK + nxt * 2048 + c * 512);
      } else if (wave == 1) {  // V(sn)
#pragma unroll
        for (int c = 0; c < 4; ++c)
          gload_lds16(vhk + (size_t)(c * 16 + sn) * 512,
                      lV + nxt * 2048 + c * 512);
      } else {  // P: new tiles pbase(s)+3, pbase(s)+4
        const int t = pbase0 + 2 * s + 3 + (wave - 2);
#pragma unroll
        for (int hf = 0; hf < 2; ++hf)
          gload_lds16(ppk + (size_t)t * 1024 + hf * 512,
                      lP + (t & 7) * 1024 + hf * 512);
      }
    }
    // ---- fragments from LDS ----
    const unsigned short* lk = lK + cur * 2048 + lane * 8;
    const unsigned short* lv = lV + cur * 2048 + lane * 8;
    s16x8 kf[4], pf[6], vf[4];
#pragma unroll
    for (int nt = 0; nt < 2; ++nt) {
      kf[2 * nt] = *(const s16x8*)(lk + nt * 1024);
      kf[2 * nt + 1] = *(const s16x8*)(lk + nt * 1024 + 512);
    }
#pragma unroll
    for (int nt = 0; nt < 3; ++nt) {
      const int t = pbase0 + 2 * s - wave + nt;
      const unsigned short* lp = lP + (t & 7) * 1024 + lane * 8;
      pf[2 * nt] = *(const s16x8*)lp;
      pf[2 * nt + 1] = *(const s16x8*)(lp + 512);
    }
#pragma unroll
    for (int nt = 0; nt < 4; ++nt) vf[nt] = *(const s16x8*)(lv + nt * 512);

    // ---- QK^T + pos MFMA ----
    f32x4 sc[2] = {fz, fz};
    __builtin_amdgcn_s_setprio(1);
#pragma unroll
    for (int nt = 0; nt < 2; ++nt) {
      sc[nt] = __builtin_amdgcn_mfma_f32_16x16x32_bf16(aqc0, kf[2 * nt],
                                                       sc[nt], 0, 0, 0);
      sc[nt] = __builtin_amdgcn_mfma_f32_16x16x32_bf16(aqc1, kf[2 * nt + 1],
                                                       sc[nt], 0, 0, 0);
    }
    f32x4 sp[3];
#pragma unroll
    for (int nt = 0; nt < 3; ++nt) {
      f32x4 t2 = fz;
      t2 = __builtin_amdgcn_mfma_f32_16x16x32_bf16(aqp0, pf[2 * nt], t2, 0, 0, 0);
      t2 = __builtin_amdgcn_mfma_f32_16x16x32_bf16(aqp1, pf[2 * nt + 1], t2, 0, 0, 0);
      sp[nt] = t2;
    }
    __builtin_amdgcn_s_setprio(0);
    // ---- rel-shift gather + softmax ----
    float sj[3][4];
#pragma unroll
    for (int j = 0; j < 3; ++j)
#pragma unroll
      for (int r = 0; r < 4; ++r) sj[j][r] = __shfl(sp[j][r], srcl[r], 64);
#pragma unroll
    for (int nt = 0; nt < 2; ++nt) {
      int tc = nt * 16 + fr;
#pragma unroll
      for (int r = 0; r < 4; ++r) {
        float pos = (fr <= crow + r) ? sj[nt][r] : sj[nt + 1][r];
        float e = EXP2(sc[nt][r] + pos);
        lsum[r] += e;
        Phw[crow + r][tc] = f2bf(e);
      }
    }
    s16x8 ah = *(const s16x8*)&Phw[fr][fc];
    __builtin_amdgcn_s_setprio(1);
#pragma unroll
    for (int nt = 0; nt < 4; ++nt)
      Oacc[nt] = __builtin_amdgcn_mfma_f32_16x16x32_bf16(ah, vf[nt], Oacc[nt],
                                                         0, 0, 0);
    __builtin_amdgcn_s_setprio(0);
    __syncthreads();  // staged(s+1) landed; buffers for s fully consumed
  }

#pragma unroll
  for (int d = 1; d < 16; d <<= 1)
#pragma unroll
    for (int r = 0; r < 4; ++r) lsum[r] += __shfl_xor(lsum[r], d, 64);
  // epilogue: ctx in packed A-fragment layout for the out GEMM
#pragma unroll
  for (int nt = 0; nt < 4; ++nt)
#pragma unroll
    for (int r = 0; r < 4; ++r) {
      float o = Oacc[nt][r] / lsum[r];
      int row = b * 512 + s0w + crow + r;
      int col = h * 64 + nt * 16 + fr;
      ctxpk[pk(row, col)] = f2bf(o);
    }
}

// ---------------------------------------------------------------------------
extern "C" void kernel_launch(void* const* d_in, const int* in_sizes, int n_in,
                              void* d_out, int out_size, void* d_ws,
                              size_t ws_size, hipStream_t stream) {
  const float* x = (const float*)d_in[0];
  const float* pe = (const float*)d_in[1];
  const float* ln_g = (const float*)d_in[2];
  const float* ln_b = (const float*)d_in[3];
  const float* Wq = (const float*)d_in[4];
  const float* bq = (const float*)d_in[5];
  const float* Wk = (const float*)d_in[6];
  const float* bk = (const float*)d_in[7];
  const float* Wv = (const float*)d_in[8];
  const float* bv = (const float*)d_in[9];
  const float* Wp = (const float*)d_in[10];
  const float* bp = (const float*)d_in[11];
  const float* cb = (const float*)d_in[12];
  const float* pb = (const float*)d_in[13];
  const float* Wo = (const float*)d_in[14];
  const float* bo = (const float*)d_in[15];
  float* out = (float*)d_out;

  char* ws = (char*)d_ws;
  size_t off = 0;
  auto alloc = [&](size_t bytes) -> char* {
    char* ptr = ws + off;
    off = (off + bytes + 255) & ~(size_t)255;
    return ptr;
  };
  // xn packed (8.4 MB) -> reused as ctx packed after proj_all completes
  unsigned short* xpk = (unsigned short*)alloc((size_t)8192 * 512 * 2);
  unsigned short* ctxpk = xpk;
  unsigned short* pepk = (unsigned short*)alloc((size_t)16384 * 512 * 2);
  unsigned short* vt_hi = (unsigned short*)alloc((size_t)8192 * 512 * 2);
  unsigned short* wqk = (unsigned short*)alloc((size_t)1024 * 512 * 2);
  unsigned short* wpm = (unsigned short*)alloc((size_t)512 * 512 * 2);
  unsigned short* wvm = (unsigned short*)alloc((size_t)512 * 512 * 2);
  unsigned short* wom = (unsigned short*)alloc((size_t)512 * 512 * 2);
  float* bqk = (float*)alloc(1024 * 4);
  unsigned short* qc = (unsigned short*)alloc((size_t)8192 * 512 * 2);
  unsigned short* qp = (unsigned short*)alloc((size_t)8192 * 512 * 2);
  unsigned short* kbuf = (unsigned short*)alloc((size_t)8192 * 512 * 2);
  unsigned short* pbuf = (unsigned short*)alloc((size_t)16384 * 512 * 2);

  if (ws_size < off) {
    fprintf(stderr, "kernel_launch: ws too small (need %zu, have %zu)\n", off,
            ws_size);
    return;
  }

  megaprep<<<6784, 256, 0, stream>>>(x, ln_g, ln_b, xpk, pe, pepk, Wq, Wk, Wp,
                                     Wv, Wo, bq, bk, wqk, wpm, wvm, wom, bqk);
  proj_all<<<1280, 256, 0, stream>>>(xpk, pepk, wqk, wpm, wvm, bqk, bp, bv,
                                     cb, pb, qc, qp, kbuf, pbuf, vt_hi);
  flash_attn<<<1024, 256, 0, stream>>>(qc, qp, kbuf, pbuf, vt_hi, ctxpk);
  out_gemm<<<256, 256, 0, stream>>>(ctxpk, wom, bo, out);
}